// Round 11
// baseline (30.990 us; speedup 1.0000x reference)
//
#include <hip/hip_runtime.h>

typedef __attribute__((ext_vector_type(8))) short bf16x8;
typedef __attribute__((ext_vector_type(16))) float f32x16;

#define SLEN 2048
#define DDIM 64
#define NH 16
#define KEPS 1e-6f
#define TILE_B 16384          // bytes per (K 8KB | VT 8KB) tile image in ws

// packed fp32x2 -> bf16x2 RNE, single VALU op
__device__ __forceinline__ unsigned cvtpk(float lo, float hi) {
    unsigned r;
    asm("v_cvt_pk_bf16_f32 %0, %1, %2" : "=v"(r) : "v"(lo), "v"(hi));
    return r;
}
__device__ __forceinline__ f32x16 mfma32x32(bf16x8 a, bf16x8 b, f32x16 c) {
    return __builtin_amdgcn_mfma_f32_32x32x16_bf16(a, b, c, 0, 0, 0);
}

// ---------------- prep: per-tile bf16 fragment images in ws (register transpose, no LDS) ----
// WS[h][kt] (16 KB): K chunks c=ks*2+hi: [c][j][8t] = bf16(K[h][kt*64+j][ks*16+hi*8+t])
//                    V (+8KB) chunks cv:  [cv][d][8t] = bf16(V[h][kt*64+(cv>>1)*16+(cv&1)*8+t][d])
__global__ void __launch_bounds__(256) prep_kernel(
    const float* __restrict__ K, const float* __restrict__ V, char* __restrict__ WS)
{
    const int b  = blockIdx.x;            // h*32 + kt
    const int h  = b >> 5;
    const int kt = b & 31;
    const int t  = threadIdx.x;
    char* chunk = WS + (size_t)b * TILE_B;

    {   // K: row j = t>>2, cols (t&3)*16.. -> two 16B fragment writes
        const int j = t >> 2, ks = t & 3, c16 = ks * 16;
        const float* src = K + ((size_t)h * SLEN + kt * 64 + j) * DDIM + c16;
        float4 a = ((const float4*)src)[0], bb = ((const float4*)src)[1];
        float4 c = ((const float4*)src)[2], d = ((const float4*)src)[3];
        uint4 lo = make_uint4(cvtpk(a.x,a.y), cvtpk(a.z,a.w), cvtpk(bb.x,bb.y), cvtpk(bb.z,bb.w));
        uint4 hi = make_uint4(cvtpk(c.x,c.y), cvtpk(c.z,c.w), cvtpk(d.x,d.y), cvtpk(d.z,d.w));
        *(uint4*)(chunk + ((size_t)((ks*2+0)*64 + j)) * 16) = lo;
        *(uint4*)(chunk + ((size_t)((ks*2+1)*64 + j)) * 16) = hi;
    }
    {   // V: 4x4 register-block transpose; rows j0..j0+3, cols d0..d0+3
        const int j0 = (t & 15) * 4, d0 = (t >> 4) * 4;
        const float* vs = V + ((size_t)h * SLEN + kt * 64 + j0) * DDIM + d0;
        float4 r0 = *(const float4*)(vs);
        float4 r1 = *(const float4*)(vs + DDIM);
        float4 r2 = *(const float4*)(vs + 2 * DDIM);
        float4 r3 = *(const float4*)(vs + 3 * DDIM);
        char* vbase = chunk + 8192;
        const int cv  = ((j0 >> 4) << 1) | ((j0 >> 3) & 1);
        const int tof = j0 & 7;           // 0 or 4
#pragma unroll
        for (int c = 0; c < 4; ++c) {
            uint2 pk = make_uint2(
                cvtpk(((const float*)&r0)[c], ((const float*)&r1)[c]),
                cvtpk(((const float*)&r2)[c], ((const float*)&r3)[c]));
            *(uint2*)(vbase + (size_t)(cv * 64 + d0 + c) * 16 + tof * 2) = pk;
        }
    }
}

// ---------------- main: uniform waves, no in-loop barriers ----------------
// 512 blocks x 256 threads (2 blocks/CU, 8 waves/CU at <=256 VGPR). Block =
// (xcd-pinned head h, pair s): slices s and 63-s. 4 waves = jb x e; EVERY wave
// processes slice s then slice 63-s (16.5 +- 0.5 tiles total -> uniform makespan).
// Fragments loaded straight from prepped ws images; K and V both prefetched one
// tile ahead. Barrier only at the two reduction points.
__global__ void __launch_bounds__(256, 2) attn_main(
    const float* __restrict__ Q, const char* __restrict__ WS, float* __restrict__ O)
{
    __shared__ float red[2][3][64][33];   // [phase][wave-1][lane][o0|o1|z]

    const int bid = blockIdx.x;
    const int xcd = bid & 7;
    const int m   = bid >> 3;             // 0..63
    const int h   = ((m & 1) << 3) | xcd; // head pinned to XCD
    const int s   = m >> 1;               // pair index 0..31

    const int tid  = threadIdx.x;
    const int w    = tid >> 6;            // wave 0..3
    const int lane = tid & 63;
    const int il   = lane & 31;
    const int hi   = lane >> 5;
    const int jb   = w & 1;               // j-subtile within 64-KV tile
    const int e    = w >> 1;              // tile parity

    const float* __restrict__ Qh = Q + (size_t)h * SLEN * DDIM;
    float* __restrict__ Oh = O + (size_t)h * SLEN * DDIM;
    const char* __restrict__ WSh = WS + (size_t)h * 32 * TILE_B;

    const int koff = (hi * 64 + jb * 32 + il) * 16;              // + ks*2048
    const int voff = 8192 + ((jb * 4 + hi) * 64 + il) * 16;      // + s16*2048 + dt*512

    auto process = [&](int slice, int phase) {
        const int g    = slice >> 1;
        const int half = slice & 1;
        const int q0   = slice * 32;

        // Q fragments (B-frag of 32x32x16): lane holds Q[q0+il][ks*16+hi*8+t]
        bf16x8 qf[4];
#pragma unroll
        for (int ks = 0; ks < 4; ++ks) {
            const float* src = Qh + (size_t)(q0 + il) * DDIM + ks * 16 + hi * 8;
            float4 a = *reinterpret_cast<const float4*>(src);
            float4 b = *reinterpret_cast<const float4*>(src + 4);
            uint4 uq = make_uint4(cvtpk(a.x, a.y), cvtpk(a.z, a.w),
                                  cvtpk(b.x, b.y), cvtpk(b.z, b.w));
            qf[ks] = *reinterpret_cast<bf16x8*>(&uq);
        }

        f32x16 o0, o1;
#pragma unroll
        for (int rr = 0; rr < 16; ++rr) { o0[rr] = 0.f; o1[rr] = 0.f; }
        float z = 0.f;

        const int ktend = g - ((jb > half) ? 1 : 0);   // jb>half: diag tile fully masked

        if (e <= ktend) {
            const char* kb = WSh + (size_t)e * TILE_B + koff;
            bf16x8 kf0 = *(const bf16x8*)(kb);
            bf16x8 kf1 = *(const bf16x8*)(kb + 2048);
            bf16x8 kf2 = *(const bf16x8*)(kb + 4096);
            bf16x8 kf3 = *(const bf16x8*)(kb + 6144);
            const char* vb = WSh + (size_t)e * TILE_B + voff;
            bf16x8 v00 = *(const bf16x8*)(vb);
            bf16x8 v01 = *(const bf16x8*)(vb + 512);
            bf16x8 v10 = *(const bf16x8*)(vb + 2048);
            bf16x8 v11 = *(const bf16x8*)(vb + 2560);

            for (int kt = e; kt <= ktend; kt += 2) {
                __builtin_amdgcn_s_setprio(1);
                // QK^T (swapped): S^T[32j x 32i]
                f32x16 sv;
#pragma unroll
                for (int rr = 0; rr < 16; ++rr) sv[rr] = 0.f;
                sv = mfma32x32(kf0, qf[0], sv);
                sv = mfma32x32(kf1, qf[1], sv);
                sv = mfma32x32(kf2, qf[2], sv);
                sv = mfma32x32(kf3, qf[3], sv);
                __builtin_amdgcn_s_setprio(0);

                // prefetch K frags for tile kt+2
                if (kt + 2 <= ktend) {
                    const char* nb = WSh + (size_t)(kt + 2) * TILE_B + koff;
                    kf0 = *(const bf16x8*)(nb);
                    kf1 = *(const bf16x8*)(nb + 2048);
                    kf2 = *(const bf16x8*)(nb + 4096);
                    kf3 = *(const bf16x8*)(nb + 6144);
                }

                // lane: S^T[j=(rr&3)+8*(rr>>2)+4*hi][i=il]; pv = (s/8)^2 = s^2/64
                const bool tri = (kt == g) && (jb == half);
#pragma unroll
                for (int rr = 0; rr < 16; ++rr) {
                    float x = sv[rr];
                    x = x * x * 0.015625f;
                    if (tri) {
                        int jl = (rr & 3) + 8 * (rr >> 2) + 4 * hi;
                        if (jl > il) x = 0.f;
                    }
                    sv[rr] = x;
                }
                {
                    float a0 = (sv[0] + sv[1]) + (sv[2] + sv[3]);
                    float a1 = (sv[4] + sv[5]) + (sv[6] + sv[7]);
                    float a2 = (sv[8] + sv[9]) + (sv[10] + sv[11]);
                    float a3 = (sv[12] + sv[13]) + (sv[14] + sv[15]);
                    z += (a0 + a1) + (a2 + a3);
                }

                // pack P (cvt_pk + permlane32_swap) and PV MFMAs
                __builtin_amdgcn_s_setprio(1);
                {
                    unsigned X  = cvtpk(sv[0], sv[1]);
                    unsigned Xp = cvtpk(sv[2], sv[3]);
                    unsigned Y  = cvtpk(sv[4], sv[5]);
                    unsigned Yp = cvtpk(sv[6], sv[7]);
                    asm("v_permlane32_swap_b32 %0, %1" : "+v"(X), "+v"(Y));
                    asm("v_permlane32_swap_b32 %0, %1" : "+v"(Xp), "+v"(Yp));
                    uint4 aw = make_uint4(X, Xp, Y, Yp);
                    bf16x8 pf = *reinterpret_cast<bf16x8*>(&aw);
                    o0 = mfma32x32(pf, v00, o0);
                    o1 = mfma32x32(pf, v01, o1);
                }
                {
                    unsigned X  = cvtpk(sv[8],  sv[9]);
                    unsigned Xp = cvtpk(sv[10], sv[11]);
                    unsigned Y  = cvtpk(sv[12], sv[13]);
                    unsigned Yp = cvtpk(sv[14], sv[15]);
                    asm("v_permlane32_swap_b32 %0, %1" : "+v"(X), "+v"(Y));
                    asm("v_permlane32_swap_b32 %0, %1" : "+v"(Xp), "+v"(Yp));
                    uint4 aw = make_uint4(X, Xp, Y, Yp);
                    bf16x8 pf = *reinterpret_cast<bf16x8*>(&aw);
                    o0 = mfma32x32(pf, v10, o0);
                    o1 = mfma32x32(pf, v11, o1);
                }
                __builtin_amdgcn_s_setprio(0);

                // prefetch V frags for tile kt+2 (consumed at end of next iter)
                if (kt + 2 <= ktend) {
                    const char* nv = WSh + (size_t)(kt + 2) * TILE_B + voff;
                    v00 = *(const bf16x8*)(nv);
                    v01 = *(const bf16x8*)(nv + 512);
                    v10 = *(const bf16x8*)(nv + 2048);
                    v11 = *(const bf16x8*)(nv + 2560);
                }
            }
        }

        // reduce 4 wave-partials (uniform work -> waves arrive together)
        z += __shfl_xor(z, 32);
        if (w != 0) {
            float* r = &red[phase][w - 1][lane][0];
#pragma unroll
            for (int rr = 0; rr < 16; ++rr) { r[rr] = o0[rr]; r[16 + rr] = o1[rr]; }
            r[32] = z;
        }
        __syncthreads();
        if (w == 0) {
#pragma unroll
            for (int pp = 0; pp < 3; ++pp) {
                const float* r = &red[phase][pp][lane][0];
#pragma unroll
                for (int rr = 0; rr < 16; ++rr) { o0[rr] += r[rr]; o1[rr] += r[16 + rr]; }
                z += r[32];
            }
            const float invl = 1.f / (z + KEPS);   // lane il: inv for row q0+il
#pragma unroll
            for (int rr = 0; rr < 16; ++rr) {
                const int rl = (rr & 3) + 8 * (rr >> 2) + 4 * hi;
                const float inv = __shfl(invl, rl);
                Oh[(size_t)(q0 + rl) * DDIM + il]      = o0[rr] * inv;
                Oh[(size_t)(q0 + rl) * DDIM + 32 + il] = o1[rr] * inv;
            }
        }
    };

    process(s, 0);          // light slice
    process(63 - s, 1);     // heavy slice  (total per wave uniform)
}

// ---- correctness-only fallback when ws is unavailable ----
__global__ void __launch_bounds__(512, 4) attn_fp32(
    const float* __restrict__ Q, const float* __restrict__ K,
    const float* __restrict__ V, float* __restrict__ O)
{
    __shared__ float red[2][3][64][33];
    const int bid = blockIdx.x;
    const int xcd = bid & 7;
    const int m   = bid >> 3;
    const int h   = xcd | ((m & 1) << 3);
    const int c   = m >> 1;
    const int tid  = threadIdx.x;
    const int w    = tid >> 6;
    const int lane = tid & 63;
    const int il   = lane & 31;
    const int hi   = lane >> 5;
    const int msel = w >> 2;
    const int jb   = (w >> 1) & 1;
    const int e    = w & 1;
    const int g    = msel ? (31 - c) : c;
    const int half = msel;
    const int q0   = g * 64 + half * 32;

    const float* Qh = Q + (size_t)h * SLEN * DDIM;
    const float* Kh = K + (size_t)h * SLEN * DDIM;
    const float* Vh = V + (size_t)h * SLEN * DDIM;
    float* Oh = O + (size_t)h * SLEN * DDIM;

    bf16x8 qf[4];
#pragma unroll
    for (int ks = 0; ks < 4; ++ks) {
        const float* src = Qh + (size_t)(q0 + il) * DDIM + ks * 16 + hi * 8;
        float4 a = *reinterpret_cast<const float4*>(src);
        float4 b = *reinterpret_cast<const float4*>(src + 4);
        uint4 uq = make_uint4(cvtpk(a.x, a.y), cvtpk(a.z, a.w),
                              cvtpk(b.x, b.y), cvtpk(b.z, b.w));
        qf[ks] = *reinterpret_cast<bf16x8*>(&uq);
    }
    f32x16 oacc0, oacc1;
#pragma unroll
    for (int rr = 0; rr < 16; ++rr) { oacc0[rr] = 0.f; oacc1[rr] = 0.f; }
    float zacc = 0.f;
    const int ktend = g - ((jb > half) ? 1 : 0);

    for (int kt = e; kt <= ktend; kt += 2) {
        f32x16 sv;
#pragma unroll
        for (int rr = 0; rr < 16; ++rr) sv[rr] = 0.f;
#pragma unroll
        for (int ks = 0; ks < 4; ++ks) {
            const float* src = Kh + (size_t)(kt * 64 + jb * 32 + il) * DDIM + ks * 16 + hi * 8;
            float4 a = *reinterpret_cast<const float4*>(src);
            float4 b = *reinterpret_cast<const float4*>(src + 4);
            uint4 uk = make_uint4(cvtpk(a.x, a.y), cvtpk(a.z, a.w),
                                  cvtpk(b.x, b.y), cvtpk(b.z, b.w));
            sv = mfma32x32(*reinterpret_cast<bf16x8*>(&uk), qf[ks], sv);
        }
        const bool tri = (kt == g) && (jb == half);
#pragma unroll
        for (int rr = 0; rr < 16; ++rr) {
            float x = sv[rr];
            x = x * x * 0.015625f;
            if (tri) {
                int jl = (rr & 3) + 8 * (rr >> 2) + 4 * hi;
                if (jl > il) x = 0.f;
            }
            sv[rr] = x;
            zacc += x;
        }
#pragma unroll
        for (int s16 = 0; s16 < 2; ++s16) {
            unsigned X  = cvtpk(sv[8*s16+0], sv[8*s16+1]);
            unsigned Xp = cvtpk(sv[8*s16+2], sv[8*s16+3]);
            unsigned Y  = cvtpk(sv[8*s16+4], sv[8*s16+5]);
            unsigned Yp = cvtpk(sv[8*s16+6], sv[8*s16+7]);
            asm("v_permlane32_swap_b32 %0, %1" : "+v"(X), "+v"(Y));
            asm("v_permlane32_swap_b32 %0, %1" : "+v"(Xp), "+v"(Yp));
            uint4 aw = make_uint4(X, Xp, Y, Yp);
            bf16x8 pf = *reinterpret_cast<bf16x8*>(&aw);
#pragma unroll
            for (int dt = 0; dt < 2; ++dt) {
                float v8[8];
#pragma unroll
                for (int t = 0; t < 8; ++t)
                    v8[t] = Vh[(size_t)(kt * 64 + (jb * 2 + s16) * 16 + hi * 8 + t) * DDIM + dt * 32 + il];
                uint4 uv = make_uint4(cvtpk(v8[0], v8[1]), cvtpk(v8[2], v8[3]),
                                      cvtpk(v8[4], v8[5]), cvtpk(v8[6], v8[7]));
                bf16x8 vf = *reinterpret_cast<bf16x8*>(&uv);
                if (dt == 0) oacc0 = mfma32x32(pf, vf, oacc0);
                else         oacc1 = mfma32x32(pf, vf, oacc1);
            }
        }
    }

    zacc += __shfl_xor(zacc, 32);
    const int sw = w & 3;
    if (sw != 0) {
        float* r = &red[msel][sw - 1][lane][0];
#pragma unroll
        for (int rr = 0; rr < 16; ++rr) { r[rr] = oacc0[rr]; r[16 + rr] = oacc1[rr]; }
        r[32] = zacc;
    }
    __syncthreads();
    if (sw == 0) {
#pragma unroll
        for (int pp = 0; pp < 3; ++pp) {
            const float* r = &red[msel][pp][lane][0];
#pragma unroll
            for (int rr = 0; rr < 16; ++rr) { oacc0[rr] += r[rr]; oacc1[rr] += r[16 + rr]; }
            zacc += r[32];
        }
        const float invl = 1.f / (zacc + KEPS);
#pragma unroll
        for (int rr = 0; rr < 16; ++rr) {
            const int rl = (rr & 3) + 8 * (rr >> 2) + 4 * hi;
            const float inv = __shfl(invl, rl);
            Oh[(size_t)(q0 + rl) * DDIM + il]      = oacc0[rr] * inv;
            Oh[(size_t)(q0 + rl) * DDIM + 32 + il] = oacc1[rr] * inv;
        }
    }
}

extern "C" void kernel_launch(void* const* d_in, const int* in_sizes, int n_in,
                              void* d_out, int out_size, void* d_ws, size_t ws_size,
                              hipStream_t stream) {
    const float* q = (const float*)d_in[0];
    const float* k = (const float*)d_in[1];
    const float* v = (const float*)d_in[2];
    float* o = (float*)d_out;

    const size_t need = (size_t)NH * 32 * TILE_B;   // 8 MB
    if (ws_size >= need) {
        char* ws = (char*)d_ws;
        hipLaunchKernelGGL(prep_kernel, dim3(NH * 32), dim3(256), 0, stream, k, v, ws);
        hipLaunchKernelGGL(attn_main, dim3(512), dim3(256), 0, stream, q, ws, o);
    } else {
        hipLaunchKernelGGL(attn_fp32, dim3(512), dim3(512), 0, stream, q, k, v, o);
    }
}